// Round 3
// baseline (983.402 us; speedup 1.0000x reference)
//
#include <hip/hip_runtime.h>
#include <hip/hip_bf16.h>

// Problem constants
#define N_NODES 2048
#define EMB 16
#define NT 12
#define BT 192
#define C_COLS 12288           // BT*64
#define TD 768                 // NT*64, per-(b,node) row length in x
#define BSTRIDE (N_NODES * TD) // per-b stride in x
#define KDIM 2048              // contraction dim (nodes)

typedef unsigned short u16;
typedef unsigned int u32;
typedef __attribute__((ext_vector_type(8))) __bf16 bf16x8;
typedef __attribute__((ext_vector_type(4))) float f32x4;

__device__ __forceinline__ u16 f2bfu(float f) { // RNE fp32 -> bf16 bits
    u32 u = __float_as_uint(f);
    return (u16)((u + 0x7FFFu + ((u >> 16) & 1u)) >> 16);
}
__device__ __forceinline__ float bfu2f(u16 h) {
    return __uint_as_float(((u32)h) << 16);
}

// async 16B global->LDS (lds dest = wave-uniform base + lane*16)
__device__ __forceinline__ void gl2lds16(const void* g, void* l) {
    __builtin_amdgcn_global_load_lds(
        (const __attribute__((address_space(1))) u32*)g,
        (__attribute__((address_space(3))) u32*)l, 16, 0, 0);
}

// ---------------------------------------------------------------------------
// Kernel 1: Sb[n][m] = bf16( softmax_m( relu( E[n]·E[m] ) ) )
// ---------------------------------------------------------------------------
__global__ void supports_kernel(const float* __restrict__ E, u16* __restrict__ Sb)
{
    __shared__ float en[EMB];
    __shared__ float red[256];
    const int n = blockIdx.x;
    const int tid = threadIdx.x;
    if (tid < EMB) en[tid] = E[n * EMB + tid];
    __syncthreads();

    float v[8];
    float mx = 0.0f; // relu >= 0
    #pragma unroll
    for (int j = 0; j < 8; ++j) {
        const int m = tid + j * 256;
        const float* em = E + m * EMB;
        float acc = 0.f;
        #pragma unroll
        for (int d = 0; d < EMB; ++d) acc += en[d] * em[d];
        acc = fmaxf(acc, 0.f);
        v[j] = acc;
        mx = fmaxf(mx, acc);
    }
    red[tid] = mx;
    __syncthreads();
    for (int s = 128; s > 0; s >>= 1) {
        if (tid < s) red[tid] = fmaxf(red[tid], red[tid + s]);
        __syncthreads();
    }
    mx = red[0];
    __syncthreads();

    float sum = 0.f;
    #pragma unroll
    for (int j = 0; j < 8; ++j) { v[j] = __expf(v[j] - mx); sum += v[j]; }
    red[tid] = sum;
    __syncthreads();
    for (int s = 128; s > 0; s >>= 1) {
        if (tid < s) red[tid] += red[tid + s];
        __syncthreads();
    }
    const float inv = 1.f / red[0];
    #pragma unroll
    for (int j = 0; j < 8; ++j)
        Sb[(size_t)n * KDIM + tid + j * 256] = f2bfu(v[j] * inv);
}

// ---------------------------------------------------------------------------
// Kernel 2: xcast — XbT[c_local][m] = bf16(x[b][m][r]),  c = c0g + c_local
// ---------------------------------------------------------------------------
__global__ void xcast_kernel(const float* __restrict__ x, u16* __restrict__ XbT, int c0g)
{
    __shared__ u16 tile[64][65];
    const int tid = threadIdx.x;
    const int cg = c0g + blockIdx.x * 64;  // 64 | 768 so no b-straddle
    const int b = cg / TD;
    const int r0 = cg - b * TD;
    const int m0 = blockIdx.y * 64;
    const float* xp = x + (size_t)b * BSTRIDE + (size_t)m0 * TD + r0;

    const int lc = tid & 63;
    const int rg = tid >> 6; // 0..3
    #pragma unroll
    for (int j = 0; j < 16; ++j) {
        const int mr = j * 4 + rg;
        tile[lc][mr] = f2bfu(xp[(size_t)mr * TD + lc]);
    }
    __syncthreads();
    u16* op = XbT + (size_t)(blockIdx.x * 64) * KDIM + m0;
    #pragma unroll
    for (int j = 0; j < 16; ++j) {
        const int cr = j * 4 + rg;
        op[(size_t)cr * KDIM + lc] = tile[cr][lc];
    }
}

// ---------------------------------------------------------------------------
// Kernel 3: bf16 MFMA GEMM, 128x128 tile, BK=32, 4 waves (2x2 of 64x64).
//   MODE 0: A=Sb, B=XbT_c   -> Y1T_c[c][m] + Y1row[m][c0g+c]
//   MODE 1: A=Sb, B=Y1T_c   -> Y2row[m][c0g+c] = 2*acc - XbT_c[c][m]
// ---------------------------------------------------------------------------
template <int MODE>
__launch_bounds__(256, 3)
__global__ void mfma_gemm(const u16* __restrict__ A,
                          const u16* __restrict__ B,
                          u16* __restrict__ OutT,
                          u16* __restrict__ OutRow,
                          const u16* __restrict__ Xc,
                          int c0g)
{
    __shared__ char smem[16384];
    char* As = smem;          // [128 m][32 k] bf16
    char* Bs = smem + 8192;   // [128 c][32 k] bf16

    const int tid = threadIdx.x;
    const int lane = tid & 63;
    const int w = tid >> 6;
    const int wm = w >> 1, wn = w & 1;
    const int ln15 = lane & 15, quad = lane >> 4;

    const int m0 = blockIdx.y * 128;
    const int cb = blockIdx.x * 128;

    const int q0 = 2 * w, q1 = 2 * w + 1;
    const int srow = lane >> 2;
    const int skol = (lane & 3) * 8;
    const u16* ga0 = A + (size_t)(m0 + q0 * 16 + srow) * KDIM + skol;
    const u16* ga1 = A + (size_t)(m0 + q1 * 16 + srow) * KDIM + skol;
    const u16* gb0 = B + (size_t)(cb + q0 * 16 + srow) * KDIM + skol;
    const u16* gb1 = B + (size_t)(cb + q1 * 16 + srow) * KDIM + skol;
    char* la0 = As + q0 * 1024;
    char* la1 = As + q1 * 1024;
    char* lb0 = Bs + q0 * 1024;
    char* lb1 = Bs + q1 * 1024;

    f32x4 acc[4][4] = {};

    for (int k0 = 0; k0 < KDIM; k0 += 32) {
        __syncthreads();
        gl2lds16(ga0, la0);
        gl2lds16(ga1, la1);
        gl2lds16(gb0, lb0);
        gl2lds16(gb1, lb1);
        ga0 += 32; ga1 += 32; gb0 += 32; gb1 += 32;
        __syncthreads();

        bf16x8 af[4], bg[4];
        #pragma unroll
        for (int i = 0; i < 4; ++i) {
            af[i] = *(const bf16x8*)(As + ((wm * 64 + i * 16 + ln15) * 64 + quad * 16));
            bg[i] = *(const bf16x8*)(Bs + ((wn * 64 + i * 16 + ln15) * 64 + quad * 16));
        }
        #pragma unroll
        for (int mi = 0; mi < 4; ++mi)
            #pragma unroll
            for (int ni = 0; ni < 4; ++ni)
                acc[mi][ni] = __builtin_amdgcn_mfma_f32_16x16x32_bf16(
                    af[mi], bg[ni], acc[mi][ni], 0, 0, 0);
    }

    const int mbase = m0 + wm * 64 + quad * 4;
    const int cbase = cb + wn * 64 + ln15;
    #pragma unroll
    for (int mi = 0; mi < 4; ++mi) {
        #pragma unroll
        for (int ni = 0; ni < 4; ++ni) {
            const f32x4 v = acc[mi][ni];
            const int mm = mbase + mi * 16;
            const int cc = cbase + ni * 16;
            if (MODE == 0) {
                ushort4 u;
                u.x = f2bfu(v.x); u.y = f2bfu(v.y); u.z = f2bfu(v.z); u.w = f2bfu(v.w);
                *(ushort4*)(OutT + (size_t)cc * KDIM + mm) = u;
                u16* orow = OutRow + (size_t)mm * C_COLS + c0g + cc;
                orow[0 * C_COLS] = u.x;
                orow[1 * C_COLS] = u.y;
                orow[2 * C_COLS] = u.z;
                orow[3 * C_COLS] = u.w;
            } else {
                const ushort4 xv = *(const ushort4*)(Xc + (size_t)cc * KDIM + mm);
                u16* orow = OutRow + (size_t)mm * C_COLS + c0g + cc;
                orow[0 * C_COLS] = f2bfu(2.f * v.x - bfu2f(xv.x));
                orow[1 * C_COLS] = f2bfu(2.f * v.y - bfu2f(xv.y));
                orow[2 * C_COLS] = f2bfu(2.f * v.z - bfu2f(xv.z));
                orow[3 * C_COLS] = f2bfu(2.f * v.w - bfu2f(xv.w));
            }
        }
    }
}

// ---------------------------------------------------------------------------
// Kernel 4: wgen — precompute Wall[n][j][o][i] = bf16(sum_d E[n,d]*Wp[d,k,i,o])
// for k = NLIVE+j (the navail precomputed slices). 16 nodes/block amortizes
// the L2-resident Wp reads. Writes are i-contiguous.
// ---------------------------------------------------------------------------
__global__ void wgen_kernel(const float* __restrict__ E, const float* __restrict__ Wp,
                            u16* __restrict__ Wall, int NLIVE, int navail)
{
    __shared__ float El[16][17];
    const int tid = threadIdx.x;
    const int j = blockIdx.y;
    const int k = NLIVE + j;
    const int n0 = blockIdx.x * 16;
    El[tid >> 4][tid & 15] = E[(n0 + (tid >> 4)) * EMB + (tid & 15)];
    __syncthreads();

    const int i = tid & 63;
    const int o0 = tid >> 6;
    #pragma unroll 1
    for (int oi = 0; oi < 16; ++oi) {
        const int o = oi * 4 + o0;
        float wp[EMB];
        #pragma unroll
        for (int d = 0; d < EMB; ++d)
            wp[d] = Wp[(size_t)((d * 3 + k) * 64 + i) * 64 + o];
        #pragma unroll
        for (int nn = 0; nn < 16; ++nn) {
            float a = 0.f;
            #pragma unroll
            for (int d = 0; d < EMB; ++d) a = fmaf(El[nn][d], wp[d], a);
            Wall[((size_t)(n0 + nn) * navail + j) * 4096 + o * 64 + i] = f2bfu(a);
        }
    }
}

// ---------------------------------------------------------------------------
// Kernel 5: gconv via MFMA. One block per node; 4 waves, wave w <-> o-tile w.
// 3 chunks of 64 bt-rows. G (x|Y1|Y2 cast to bf16) in LDS [64][GLS];
// W^T per node in LDS [3][64][WTS]. NLIVE slices of W computed live from Wp,
// the rest copied from Wall.
// ---------------------------------------------------------------------------
#define GLS 200   // Gl ki-stride (elems): 400 B = 16B-aligned, 2-way banks
#define WTS 72    // Wt i-stride (elems): 144 B = 16B-aligned, 2-way banks

template <int NLIVE>
__launch_bounds__(256, 2)
__global__ void gconv_mfma(const float* __restrict__ x,
                           const float* __restrict__ E,
                           const float* __restrict__ Wp,
                           const float* __restrict__ Bp,
                           const u16* __restrict__ Y1row,
                           const u16* __restrict__ Y2row,
                           const u16* __restrict__ Wall, int navail,
                           float* __restrict__ Out)
{
    __shared__ u16 Gl[64 * GLS];      // 25600 B
    __shared__ u16 Wt[3 * 64 * WTS];  // 27648 B
    __shared__ float bias[64];
    __shared__ float en[EMB];

    const int n = blockIdx.x;
    const int tid = threadIdx.x;
    const int lane = tid & 63;
    const int w = tid >> 6;
    const int ln15 = lane & 15, quad = lane >> 4;
    const int ow = w * 16 + ln15; // this wave's output column o

    if (tid < EMB) en[tid] = E[n * EMB + tid];
    __syncthreads();

    if (tid < 64) {
        float a = 0.f;
        #pragma unroll
        for (int d = 0; d < EMB; ++d) a = fmaf(en[d], Bp[d * 64 + tid], a);
        bias[tid] = a;
    }

    // live W slices (k < NLIVE)
    #pragma unroll
    for (int k = 0; k < NLIVE; ++k) {
        const int i = tid & 63;
        const int o0 = tid >> 6;
        #pragma unroll 2
        for (int oi = 0; oi < 16; ++oi) {
            const int o = oi * 4 + o0;
            float a = 0.f;
            #pragma unroll
            for (int d = 0; d < EMB; ++d)
                a = fmaf(en[d], Wp[(size_t)((d * 3 + k) * 64 + i) * 64 + o], a);
            Wt[(k * 64 + o) * WTS + i] = f2bfu(a);
        }
    }
    // precomputed W slices (k >= NLIVE): copy 8 KB from Wall
    #pragma unroll
    for (int k = NLIVE; k < 3; ++k) {
        const u16* src = Wall + ((size_t)n * navail + (k - NLIVE)) * 4096;
        #pragma unroll
        for (int j = 0; j < 2; ++j) {
            const int task = j * 256 + tid;     // 0..511
            const int o = task >> 3;
            const int ic = (task & 7) * 8;
            *(uint4*)&Wt[(k * 64 + o) * WTS + ic] = *(const uint4*)(src + o * 64 + ic);
        }
    }

    #pragma unroll 1
    for (int ch = 0; ch < 3; ++ch) {
        __syncthreads(); // Gl free / (ch=0) Wt+bias ready-before-load phase done
        #pragma unroll
        for (int j = 0; j < 2; ++j) {
            const int task = j * 256 + tid;     // 0..511
            const int r = task >> 3;            // 0..63
            const int i = (task & 7) * 8;
            const int bt = ch * 64 + r;
            const int b = bt / NT, t = bt - b * NT;
            const float* xp = x + (size_t)b * BSTRIDE + (size_t)n * TD + t * 64 + i;
            const float4 u0 = *(const float4*)xp;
            const float4 u1 = *(const float4*)(xp + 4);
            uint4 pk;
            pk.x = f2bfu(u0.x) | ((u32)f2bfu(u0.y) << 16);
            pk.y = f2bfu(u0.z) | ((u32)f2bfu(u0.w) << 16);
            pk.z = f2bfu(u1.x) | ((u32)f2bfu(u1.y) << 16);
            pk.w = f2bfu(u1.z) | ((u32)f2bfu(u1.w) << 16);
            *(uint4*)&Gl[r * GLS + i] = pk;
            const size_t yoff = (size_t)n * C_COLS + (size_t)bt * 64 + i;
            *(uint4*)&Gl[r * GLS + 64 + i] = *(const uint4*)(Y1row + yoff);
            *(uint4*)&Gl[r * GLS + 128 + i] = *(const uint4*)(Y2row + yoff);
        }
        __syncthreads();

        const float bv = bias[ow];
        f32x4 acc[4];
        #pragma unroll
        for (int mt = 0; mt < 4; ++mt) acc[mt] = f32x4{bv, bv, bv, bv};

        #pragma unroll
        for (int ks = 0; ks < 6; ++ks) {
            const int kk = ks >> 1;
            const int ib = (ks & 1) * 32 + quad * 8;
            const bf16x8 bfrag = *(const bf16x8*)&Wt[(kk * 64 + ow) * WTS + ib];
            #pragma unroll
            for (int mt = 0; mt < 4; ++mt) {
                const bf16x8 afrag =
                    *(const bf16x8*)&Gl[(mt * 16 + ln15) * GLS + ks * 32 + quad * 8];
                acc[mt] = __builtin_amdgcn_mfma_f32_16x16x32_bf16(afrag, bfrag, acc[mt], 0, 0, 0);
            }
        }

        #pragma unroll
        for (int mt = 0; mt < 4; ++mt) {
            #pragma unroll
            for (int rg = 0; rg < 4; ++rg) {
                const int bt = ch * 64 + mt * 16 + quad * 4 + rg;
                const int b = bt / NT, t = bt - b * NT;
                Out[(((size_t)b * N_NODES + n) * NT + t) * 64 + ow] = acc[mt][rg];
            }
        }
    }
}

// ---------------------------------------------------------------------------
// Workspace layout (runtime-adaptive, deterministic in ws_size):
//   Y1row @ 0      (48 MiB)  bf16 2048x12288
//   Y2row @ 48 M   (48 MiB)  bf16 2048x12288
//   Sb    @ 96 M   (8 MiB)   bf16 2048x2048   [dead after GEMM phase]
//   chunks@ 104 M  (2 x CW*2048*2)            [dead after GEMM phase]
//   Wall  @ 96 M   (16*navail MiB) overlays Sb+chunks, written after GEMMs
// navail = min(3, (ws-96M)/16M); NLIVE = 3-navail slices computed live.
// Round-2 profile (_ord=8 => nc=2) implies ws >= 152 MiB => navail=3.
// ---------------------------------------------------------------------------
extern "C" void kernel_launch(void* const* d_in, const int* in_sizes, int n_in,
                              void* d_out, int out_size, void* d_ws, size_t ws_size,
                              hipStream_t stream)
{
    const float* x  = (const float*)d_in[0];
    const float* E  = (const float*)d_in[1];
    const float* Wp = (const float*)d_in[2];
    const float* Bp = (const float*)d_in[3];
    float* Out = (float*)d_out;

    const size_t MiB = 1024 * 1024;
    u16* Y1row = (u16*)d_ws;
    u16* Y2row = (u16*)((char*)d_ws + 48 * MiB);
    u16* Sb    = (u16*)((char*)d_ws + 96 * MiB);
    char* chunkbase = (char*)d_ws + 104 * MiB;
    u16* Wall  = (u16*)((char*)d_ws + 96 * MiB);

    const int cands[5] = {1, 2, 3, 6, 12};
    int nc = 12;
    for (int i = 0; i < 5; ++i) {
        const size_t chunk_bytes = (size_t)(C_COLS / cands[i]) * KDIM * 2;
        if (104 * MiB + 2 * chunk_bytes <= ws_size) { nc = cands[i]; break; }
    }
    const int CW = C_COLS / nc;
    u16* XbTc = (u16*)chunkbase;
    u16* Y1Tc = (u16*)(chunkbase + (size_t)CW * KDIM * 2);

    int navail = 0;
    if (ws_size > 96 * MiB) {
        size_t sl = (ws_size - 96 * MiB) / (16 * MiB);
        navail = sl < 3 ? (int)sl : 3;
    }
    const int NLIVE = 3 - navail;

    supports_kernel<<<N_NODES, 256, 0, stream>>>(E, Sb);

    for (int c = 0; c < nc; ++c) {
        const int c0g = c * CW;
        xcast_kernel<<<dim3(CW / 64, 32), 256, 0, stream>>>(x, XbTc, c0g);
        mfma_gemm<0><<<dim3(CW / 128, 16), 256, 0, stream>>>(Sb, XbTc, Y1Tc, Y1row, nullptr, c0g);
        mfma_gemm<1><<<dim3(CW / 128, 16), 256, 0, stream>>>(Sb, Y1Tc, nullptr, Y2row, XbTc, c0g);
    }

    if (navail > 0)
        wgen_kernel<<<dim3(128, navail), 256, 0, stream>>>(E, Wp, Wall, NLIVE, navail);

    switch (NLIVE) {
        case 0: gconv_mfma<0><<<N_NODES, 256, 0, stream>>>(x, E, Wp, Bp, Y1row, Y2row, Wall, navail, Out); break;
        case 1: gconv_mfma<1><<<N_NODES, 256, 0, stream>>>(x, E, Wp, Bp, Y1row, Y2row, Wall, navail, Out); break;
        case 2: gconv_mfma<2><<<N_NODES, 256, 0, stream>>>(x, E, Wp, Bp, Y1row, Y2row, Wall, navail, Out); break;
        default: gconv_mfma<3><<<N_NODES, 256, 0, stream>>>(x, E, Wp, Bp, Y1row, Y2row, Wall, navail, Out); break;
    }
}

// Round 4
// 938.312 us; speedup vs baseline: 1.0481x; 1.0481x over previous
//
#include <hip/hip_runtime.h>
#include <hip/hip_bf16.h>

// Problem constants
#define N_NODES 2048
#define EMB 16
#define NT 12
#define BT 192
#define C_COLS 12288           // BT*64
#define TD 768                 // NT*64, per-(b,node) row length in x
#define BSTRIDE (N_NODES * TD) // per-b stride in x
#define KDIM 2048              // contraction dim (nodes)

typedef unsigned short u16;
typedef unsigned int u32;
typedef __attribute__((ext_vector_type(8))) __bf16 bf16x8;
typedef __attribute__((ext_vector_type(4))) float f32x4;

__device__ __forceinline__ u16 f2bfu(float f) { // RNE fp32 -> bf16 bits
    u32 u = __float_as_uint(f);
    return (u16)((u + 0x7FFFu + ((u >> 16) & 1u)) >> 16);
}
__device__ __forceinline__ float bfu2f(u16 h) {
    return __uint_as_float(((u32)h) << 16);
}

// async 16B global->LDS (lds dest = wave-uniform base + lane*16)
__device__ __forceinline__ void gl2lds16(const void* g, void* l) {
    __builtin_amdgcn_global_load_lds(
        (const __attribute__((address_space(1))) u32*)g,
        (__attribute__((address_space(3))) u32*)l, 16, 0, 0);
}

// ---------------------------------------------------------------------------
// Kernel 1: Sb[n][m] = bf16( softmax_m( relu( E[n]·E[m] ) ) )
// ---------------------------------------------------------------------------
__global__ void supports_kernel(const float* __restrict__ E, u16* __restrict__ Sb)
{
    __shared__ float en[EMB];
    __shared__ float red[256];
    const int n = blockIdx.x;
    const int tid = threadIdx.x;
    if (tid < EMB) en[tid] = E[n * EMB + tid];
    __syncthreads();

    float v[8];
    float mx = 0.0f; // relu >= 0
    #pragma unroll
    for (int j = 0; j < 8; ++j) {
        const int m = tid + j * 256;
        const float* em = E + m * EMB;
        float acc = 0.f;
        #pragma unroll
        for (int d = 0; d < EMB; ++d) acc += en[d] * em[d];
        acc = fmaxf(acc, 0.f);
        v[j] = acc;
        mx = fmaxf(mx, acc);
    }
    red[tid] = mx;
    __syncthreads();
    for (int s = 128; s > 0; s >>= 1) {
        if (tid < s) red[tid] = fmaxf(red[tid], red[tid + s]);
        __syncthreads();
    }
    mx = red[0];
    __syncthreads();

    float sum = 0.f;
    #pragma unroll
    for (int j = 0; j < 8; ++j) { v[j] = __expf(v[j] - mx); sum += v[j]; }
    red[tid] = sum;
    __syncthreads();
    for (int s = 128; s > 0; s >>= 1) {
        if (tid < s) red[tid] += red[tid + s];
        __syncthreads();
    }
    const float inv = 1.f / red[0];
    #pragma unroll
    for (int j = 0; j < 8; ++j)
        Sb[(size_t)n * KDIM + tid + j * 256] = f2bfu(v[j] * inv);
}

// ---------------------------------------------------------------------------
// Kernel 2: xcast — XbT[c_local][m] = bf16(x[b][m][r]),  c = c0g + c_local
// ---------------------------------------------------------------------------
__global__ void xcast_kernel(const float* __restrict__ x, u16* __restrict__ XbT, int c0g)
{
    __shared__ u16 tile[64][65];
    const int tid = threadIdx.x;
    const int cg = c0g + blockIdx.x * 64;  // 64 | 768 so no b-straddle
    const int b = cg / TD;
    const int r0 = cg - b * TD;
    const int m0 = blockIdx.y * 64;
    const float* xp = x + (size_t)b * BSTRIDE + (size_t)m0 * TD + r0;

    const int lc = tid & 63;
    const int rg = tid >> 6; // 0..3
    #pragma unroll
    for (int j = 0; j < 16; ++j) {
        const int mr = j * 4 + rg;
        tile[lc][mr] = f2bfu(xp[(size_t)mr * TD + lc]);
    }
    __syncthreads();
    u16* op = XbT + (size_t)(blockIdx.x * 64) * KDIM + m0;
    #pragma unroll
    for (int j = 0; j < 16; ++j) {
        const int cr = j * 4 + rg;
        op[(size_t)cr * KDIM + lc] = tile[cr][lc];
    }
}

// ---------------------------------------------------------------------------
// Kernel 3: bf16 MFMA GEMM, 128x128 tile, BK=32, 4 waves (2x2 of 64x64).
//   MODE 0: A=Sb, B=XbT_c   -> Y1T_c[c][m] + Y1row[m][c0g+c]
//   MODE 1: A=Sb, B=Y1T_c   -> Y2row[m][c0g+c] = 2*acc - XbT_c[c][m]
// ---------------------------------------------------------------------------
template <int MODE>
__launch_bounds__(256, 3)
__global__ void mfma_gemm(const u16* __restrict__ A,
                          const u16* __restrict__ B,
                          u16* __restrict__ OutT,
                          u16* __restrict__ OutRow,
                          const u16* __restrict__ Xc,
                          int c0g)
{
    __shared__ char smem[16384];
    char* As = smem;          // [128 m][32 k] bf16
    char* Bs = smem + 8192;   // [128 c][32 k] bf16

    const int tid = threadIdx.x;
    const int lane = tid & 63;
    const int w = tid >> 6;
    const int wm = w >> 1, wn = w & 1;
    const int ln15 = lane & 15, quad = lane >> 4;

    const int m0 = blockIdx.y * 128;
    const int cb = blockIdx.x * 128;

    const int q0 = 2 * w, q1 = 2 * w + 1;
    const int srow = lane >> 2;
    const int skol = (lane & 3) * 8;
    const u16* ga0 = A + (size_t)(m0 + q0 * 16 + srow) * KDIM + skol;
    const u16* ga1 = A + (size_t)(m0 + q1 * 16 + srow) * KDIM + skol;
    const u16* gb0 = B + (size_t)(cb + q0 * 16 + srow) * KDIM + skol;
    const u16* gb1 = B + (size_t)(cb + q1 * 16 + srow) * KDIM + skol;
    char* la0 = As + q0 * 1024;
    char* la1 = As + q1 * 1024;
    char* lb0 = Bs + q0 * 1024;
    char* lb1 = Bs + q1 * 1024;

    f32x4 acc[4][4] = {};

    for (int k0 = 0; k0 < KDIM; k0 += 32) {
        __syncthreads();
        gl2lds16(ga0, la0);
        gl2lds16(ga1, la1);
        gl2lds16(gb0, lb0);
        gl2lds16(gb1, lb1);
        ga0 += 32; ga1 += 32; gb0 += 32; gb1 += 32;
        __syncthreads();

        bf16x8 af[4], bg[4];
        #pragma unroll
        for (int i = 0; i < 4; ++i) {
            af[i] = *(const bf16x8*)(As + ((wm * 64 + i * 16 + ln15) * 64 + quad * 16));
            bg[i] = *(const bf16x8*)(Bs + ((wn * 64 + i * 16 + ln15) * 64 + quad * 16));
        }
        #pragma unroll
        for (int mi = 0; mi < 4; ++mi)
            #pragma unroll
            for (int ni = 0; ni < 4; ++ni)
                acc[mi][ni] = __builtin_amdgcn_mfma_f32_16x16x32_bf16(
                    af[mi], bg[ni], acc[mi][ni], 0, 0, 0);
    }

    const int mbase = m0 + wm * 64 + quad * 4;
    const int cbase = cb + wn * 64 + ln15;
    #pragma unroll
    for (int mi = 0; mi < 4; ++mi) {
        #pragma unroll
        for (int ni = 0; ni < 4; ++ni) {
            const f32x4 v = acc[mi][ni];
            const int mm = mbase + mi * 16;
            const int cc = cbase + ni * 16;
            if (MODE == 0) {
                ushort4 u;
                u.x = f2bfu(v.x); u.y = f2bfu(v.y); u.z = f2bfu(v.z); u.w = f2bfu(v.w);
                *(ushort4*)(OutT + (size_t)cc * KDIM + mm) = u;
                u16* orow = OutRow + (size_t)mm * C_COLS + c0g + cc;
                orow[0 * C_COLS] = u.x;
                orow[1 * C_COLS] = u.y;
                orow[2 * C_COLS] = u.z;
                orow[3 * C_COLS] = u.w;
            } else {
                const ushort4 xv = *(const ushort4*)(Xc + (size_t)cc * KDIM + mm);
                u16* orow = OutRow + (size_t)mm * C_COLS + c0g + cc;
                orow[0 * C_COLS] = f2bfu(2.f * v.x - bfu2f(xv.x));
                orow[1 * C_COLS] = f2bfu(2.f * v.y - bfu2f(xv.y));
                orow[2 * C_COLS] = f2bfu(2.f * v.z - bfu2f(xv.z));
                orow[3 * C_COLS] = f2bfu(2.f * v.w - bfu2f(xv.w));
            }
        }
    }
}

// ---------------------------------------------------------------------------
// Kernel 4: wgen v2 — coalesced. 8 nodes x 1 k-slice per block.
// Read Wp with lane<->o (256 B contiguous per wave); accumulate over d in
// registers; write transposed tile Tl[nn][o][i] in LDS (i-stride 72 for 16B
// alignment); stream out Wall[n][j][o][i] with i contiguous (coalesced 1 KB
// runs per wave).
// ---------------------------------------------------------------------------
__global__ void wgen_kernel(const float* __restrict__ E, const float* __restrict__ Wp,
                            u16* __restrict__ Wall, int NLIVE, int navail)
{
    __shared__ u16 Tl[8 * 64 * 72];   // 73728 B
    __shared__ float El[8][17];
    const int tid = threadIdx.x;
    const int j = blockIdx.y;
    const int k = NLIVE + j;
    const int n0 = blockIdx.x * 8;
    if (tid < 128) El[tid >> 4][tid & 15] = E[(n0 + (tid >> 4)) * EMB + (tid & 15)];
    __syncthreads();

    const int o = tid & 63;
    const int ig = tid >> 6;           // 0..3
    #pragma unroll 1
    for (int it = 0; it < 16; ++it) {
        const int i = it * 4 + ig;
        float wp[EMB];
        #pragma unroll
        for (int d = 0; d < EMB; ++d)
            wp[d] = Wp[(size_t)((d * 3 + k) * 64 + i) * 64 + o];  // lane<->o: coalesced
        #pragma unroll
        for (int nn = 0; nn < 8; ++nn) {
            float a = 0.f;
            #pragma unroll
            for (int d = 0; d < EMB; ++d) a = fmaf(El[nn][d], wp[d], a);
            Tl[(nn * 64 + o) * 72 + i] = f2bfu(a);
        }
    }
    __syncthreads();

    #pragma unroll 1
    for (int nn = 0; nn < 8; ++nn) {
        u16* dst = Wall + ((size_t)(n0 + nn) * navail + j) * 4096;
        #pragma unroll
        for (int jj = 0; jj < 2; ++jj) {
            const int task = jj * 256 + tid;   // 0..511
            const int oo = task >> 3;
            const int i0 = (task & 7) * 8;
            const uint4 v = *(const uint4*)&Tl[(nn * 64 + oo) * 72 + i0];
            *(uint4*)(dst + oo * 64 + i0) = v;
        }
    }
}

// ---------------------------------------------------------------------------
// Kernel 5: gconv via MFMA. One block per node; 4 waves, wave w <-> o-tile w.
// ---------------------------------------------------------------------------
#define GLS 200   // Gl ki-stride (elems)
#define WTS 72    // Wt i-stride (elems)

template <int NLIVE>
__launch_bounds__(256, 2)
__global__ void gconv_mfma(const float* __restrict__ x,
                           const float* __restrict__ E,
                           const float* __restrict__ Wp,
                           const float* __restrict__ Bp,
                           const u16* __restrict__ Y1row,
                           const u16* __restrict__ Y2row,
                           const u16* __restrict__ Wall, int navail,
                           float* __restrict__ Out)
{
    __shared__ u16 Gl[64 * GLS];      // 25600 B
    __shared__ u16 Wt[3 * 64 * WTS];  // 27648 B
    __shared__ float bias[64];
    __shared__ float en[EMB];

    const int n = blockIdx.x;
    const int tid = threadIdx.x;
    const int lane = tid & 63;
    const int w = tid >> 6;
    const int ln15 = lane & 15, quad = lane >> 4;
    const int ow = w * 16 + ln15;

    if (tid < EMB) en[tid] = E[n * EMB + tid];
    __syncthreads();

    if (tid < 64) {
        float a = 0.f;
        #pragma unroll
        for (int d = 0; d < EMB; ++d) a = fmaf(en[d], Bp[d * 64 + tid], a);
        bias[tid] = a;
    }

    // live W slices (k < NLIVE) — fallback path only
    #pragma unroll
    for (int k = 0; k < NLIVE; ++k) {
        const int i = tid & 63;
        const int o0 = tid >> 6;
        #pragma unroll 2
        for (int oi = 0; oi < 16; ++oi) {
            const int o = oi * 4 + o0;
            float a = 0.f;
            #pragma unroll
            for (int d = 0; d < EMB; ++d)
                a = fmaf(en[d], Wp[(size_t)((d * 3 + k) * 64 + i) * 64 + o], a);
            Wt[(k * 64 + o) * WTS + i] = f2bfu(a);
        }
    }
    // precomputed W slices: copy 8 KB from Wall
    #pragma unroll
    for (int k = NLIVE; k < 3; ++k) {
        const u16* src = Wall + ((size_t)n * navail + (k - NLIVE)) * 4096;
        #pragma unroll
        for (int j = 0; j < 2; ++j) {
            const int task = j * 256 + tid;
            const int o = task >> 3;
            const int ic = (task & 7) * 8;
            *(uint4*)&Wt[(k * 64 + o) * WTS + ic] = *(const uint4*)(src + o * 64 + ic);
        }
    }

    #pragma unroll 1
    for (int ch = 0; ch < 3; ++ch) {
        __syncthreads();
        #pragma unroll
        for (int j = 0; j < 2; ++j) {
            const int task = j * 256 + tid;
            const int r = task >> 3;
            const int i = (task & 7) * 8;
            const int bt = ch * 64 + r;
            const int b = bt / NT, t = bt - b * NT;
            const float* xp = x + (size_t)b * BSTRIDE + (size_t)n * TD + t * 64 + i;
            const float4 u0 = *(const float4*)xp;
            const float4 u1 = *(const float4*)(xp + 4);
            uint4 pk;
            pk.x = f2bfu(u0.x) | ((u32)f2bfu(u0.y) << 16);
            pk.y = f2bfu(u0.z) | ((u32)f2bfu(u0.w) << 16);
            pk.z = f2bfu(u1.x) | ((u32)f2bfu(u1.y) << 16);
            pk.w = f2bfu(u1.z) | ((u32)f2bfu(u1.w) << 16);
            *(uint4*)&Gl[r * GLS + i] = pk;
            const size_t yoff = (size_t)n * C_COLS + (size_t)bt * 64 + i;
            *(uint4*)&Gl[r * GLS + 64 + i] = *(const uint4*)(Y1row + yoff);
            *(uint4*)&Gl[r * GLS + 128 + i] = *(const uint4*)(Y2row + yoff);
        }
        __syncthreads();

        const float bv = bias[ow];
        f32x4 acc[4];
        #pragma unroll
        for (int mt = 0; mt < 4; ++mt) acc[mt] = f32x4{bv, bv, bv, bv};

        #pragma unroll
        for (int ks = 0; ks < 6; ++ks) {
            const int kk = ks >> 1;
            const int ib = (ks & 1) * 32 + quad * 8;
            const bf16x8 bfrag = *(const bf16x8*)&Wt[(kk * 64 + ow) * WTS + ib];
            #pragma unroll
            for (int mt = 0; mt < 4; ++mt) {
                const bf16x8 afrag =
                    *(const bf16x8*)&Gl[(mt * 16 + ln15) * GLS + ks * 32 + quad * 8];
                acc[mt] = __builtin_amdgcn_mfma_f32_16x16x32_bf16(afrag, bfrag, acc[mt], 0, 0, 0);
            }
        }

        #pragma unroll
        for (int mt = 0; mt < 4; ++mt) {
            #pragma unroll
            for (int rg = 0; rg < 4; ++rg) {
                const int bt = ch * 64 + mt * 16 + quad * 4 + rg;
                const int b = bt / NT, t = bt - b * NT;
                Out[(((size_t)b * N_NODES + n) * NT + t) * 64 + ow] = acc[mt][rg];
            }
        }
    }
}

// ---------------------------------------------------------------------------
// Workspace layout (runtime-adaptive, deterministic in ws_size):
//   Y1row @ 0      (48 MiB), Y2row @ 48 M (48 MiB)
//   Sb @ 96 M (8 MiB, dead after GEMMs), chunks @ 104 M (dead after GEMMs)
//   Wall @ 96 M (16*navail MiB) overlays Sb+chunks after GEMM phase
// ---------------------------------------------------------------------------
extern "C" void kernel_launch(void* const* d_in, const int* in_sizes, int n_in,
                              void* d_out, int out_size, void* d_ws, size_t ws_size,
                              hipStream_t stream)
{
    const float* x  = (const float*)d_in[0];
    const float* E  = (const float*)d_in[1];
    const float* Wp = (const float*)d_in[2];
    const float* Bp = (const float*)d_in[3];
    float* Out = (float*)d_out;

    const size_t MiB = 1024 * 1024;
    u16* Y1row = (u16*)d_ws;
    u16* Y2row = (u16*)((char*)d_ws + 48 * MiB);
    u16* Sb    = (u16*)((char*)d_ws + 96 * MiB);
    char* chunkbase = (char*)d_ws + 104 * MiB;
    u16* Wall  = (u16*)((char*)d_ws + 96 * MiB);

    const int cands[5] = {1, 2, 3, 6, 12};
    int nc = 12;
    for (int i = 0; i < 5; ++i) {
        const size_t chunk_bytes = (size_t)(C_COLS / cands[i]) * KDIM * 2;
        if (104 * MiB + 2 * chunk_bytes <= ws_size) { nc = cands[i]; break; }
    }
    const int CW = C_COLS / nc;
    u16* XbTc = (u16*)chunkbase;
    u16* Y1Tc = (u16*)(chunkbase + (size_t)CW * KDIM * 2);

    int navail = 0;
    if (ws_size > 96 * MiB) {
        size_t sl = (ws_size - 96 * MiB) / (16 * MiB);
        navail = sl < 3 ? (int)sl : 3;
    }
    const int NLIVE = 3 - navail;

    supports_kernel<<<N_NODES, 256, 0, stream>>>(E, Sb);

    for (int c = 0; c < nc; ++c) {
        const int c0g = c * CW;
        xcast_kernel<<<dim3(CW / 64, 32), 256, 0, stream>>>(x, XbTc, c0g);
        mfma_gemm<0><<<dim3(CW / 128, 16), 256, 0, stream>>>(Sb, XbTc, Y1Tc, Y1row, nullptr, c0g);
        mfma_gemm<1><<<dim3(CW / 128, 16), 256, 0, stream>>>(Sb, Y1Tc, nullptr, Y2row, XbTc, c0g);
    }

    if (navail > 0)
        wgen_kernel<<<dim3(N_NODES / 8, navail), 256, 0, stream>>>(E, Wp, Wall, NLIVE, navail);

    switch (NLIVE) {
        case 0: gconv_mfma<0><<<N_NODES, 256, 0, stream>>>(x, E, Wp, Bp, Y1row, Y2row, Wall, navail, Out); break;
        case 1: gconv_mfma<1><<<N_NODES, 256, 0, stream>>>(x, E, Wp, Bp, Y1row, Y2row, Wall, navail, Out); break;
        case 2: gconv_mfma<2><<<N_NODES, 256, 0, stream>>>(x, E, Wp, Bp, Y1row, Y2row, Wall, navail, Out); break;
        default: gconv_mfma<3><<<N_NODES, 256, 0, stream>>>(x, E, Wp, Bp, Y1row, Y2row, Wall, navail, Out); break;
    }
}